// Round 1
// baseline (122.225 us; speedup 1.0000x reference)
//
#include <hip/hip_runtime.h>

#define NB 8
#define NC 256
#define NN 1024

typedef unsigned short u16;
typedef unsigned int u32;
typedef __attribute__((ext_vector_type(8))) short short8;
typedef __attribute__((ext_vector_type(4))) float f32x4;

__device__ __forceinline__ u16 f2b(float f){ union{float ff;u32 i;}v; v.ff=f; u32 r=v.i+0x7FFFu+((v.i>>16)&1u); return (u16)(r>>16); }
__device__ __forceinline__ float b2f(u16 p){ union{u32 i;float f;}v; v.i=((u32)p)<<16; return v.f; }
__device__ __forceinline__ float pklo(u32 p){ union{u32 i;float f;}v; v.i=p<<16; return v.f; }
__device__ __forceinline__ float pkhi(u32 p){ union{u32 i;float f;}v; v.i=p&0xFFFF0000u; return v.f; }

// fold SCALE (1/sqrt(32)) * log2(e) into stored q so softmax is exp2(q'.k)
#define QSC 0.25503486f

union FR { uint4 u; short8 s; };

// K1: merged casts. Blocks 0..255: qkv_w+proj_w fp32->bf16 flat.
// Blocks 256..511: x[b,c,n] fp32 -> xt[b,n,c] bf16 (LDS tile transpose).
__global__ void __launch_bounds__(256) k_cast(const float* __restrict__ qkvw,
                                              const float* __restrict__ projw,
                                              const float* __restrict__ x,
                                              u16* __restrict__ wb,
                                              u16* __restrict__ xt){
  __shared__ u16 lt[64][136];
  const int tid = threadIdx.x;
  if (blockIdx.x < 256){
    const int idx = blockIdx.x*256 + tid;              // 65536 float4 groups
    const float* src = (idx < 49152) ? (qkvw + (size_t)idx*4)
                                     : (projw + (size_t)(idx-49152)*4);
    float4 a = *(const float4*)src;
    uint2 o;
    o.x = (u32)f2b(a.x) | ((u32)f2b(a.y)<<16);
    o.y = (u32)f2b(a.z) | ((u32)f2b(a.w)<<16);
    *(uint2*)(wb + (size_t)idx*4) = o;
    return;
  }
  const int bx = blockIdx.x - 256;
  const int n0 = (bx & 15)*64, c0 = ((bx>>4)&1)*128, b = bx>>5;
  #pragma unroll
  for (int cc = 0; cc < 4; cc++){
    const int c = c0 + cc*32 + (tid>>3);
    const int ns = (tid&7)*8;
    const float* src = x + ((size_t)(b*NC + c))*NN + n0 + ns;
    float4 a = *(const float4*)src;
    float4 d = *(const float4*)(src+4);
    const int cl = c - c0;
    lt[ns+0][cl] = f2b(a.x); lt[ns+1][cl] = f2b(a.y);
    lt[ns+2][cl] = f2b(a.z); lt[ns+3][cl] = f2b(a.w);
    lt[ns+4][cl] = f2b(d.x); lt[ns+5][cl] = f2b(d.y);
    lt[ns+6][cl] = f2b(d.z); lt[ns+7][cl] = f2b(d.w);
  }
  __syncthreads();
  #pragma unroll
  for (int p = 0; p < 4; p++){
    const int flat = p*256 + tid;
    const int row = flat >> 4, seg = flat & 15;
    uint4 d = *(uint4*)&lt[row][seg*8];
    *(uint4*)(xt + ((size_t)(b*NN + n0 + row))*NC + c0 + seg*8) = d;
  }
}

// K2: qkv = Wqkv @ x via MFMA. grid (24,4,8), block 256 = 4 waves of 32o x 64n.
//   ot 0-7  : q -> qt[b,h][n][32] bf16 (scaled by QSC), LDS repack
//   ot 8-15 : k -> kt[b,h][n][32] bf16
//   ot 16-23: v -> v[b,c][n] bf16 (direct scalar stores)
__global__ void __launch_bounds__(256) k_qkv(const u16* __restrict__ wqb,
                                             const u16* __restrict__ xt,
                                             u16* __restrict__ qt,
                                             u16* __restrict__ kt,
                                             u16* __restrict__ v){
  const int ot = blockIdx.x, nt = blockIdx.y, b = blockIdx.z;
  const int o0 = ot*32;
  const int tid = threadIdx.x, wv = tid>>6, lane = tid&63;
  const int l15 = lane&15, quad = lane>>4;
  const int n0w = nt*256 + wv*64;
  __shared__ u16 swq[32][264];
  __shared__ u16 s2[4][64][40];
  #pragma unroll
  for (int i = 0; i < 4; i++){
    const int flat = i*256 + tid;
    const int row = flat >> 5, col = flat & 31;
    *(uint4*)&swq[row][col*8] = *(const uint4*)(wqb + (size_t)(o0+row)*NC + col*8);
  }
  __syncthreads();
  f32x4 acc[2][4];
  #pragma unroll
  for (int mt = 0; mt < 2; mt++)
    #pragma unroll
    for (int nt2 = 0; nt2 < 4; nt2++) acc[mt][nt2] = (f32x4){0.f,0.f,0.f,0.f};
  const u16* xb = xt + ((size_t)(b*NN + n0w))*NC;
  for (int k0 = 0; k0 < 256; k0 += 32){
    FR af[2], bf[4];
    af[0].u = *(uint4*)&swq[l15][k0 + quad*8];
    af[1].u = *(uint4*)&swq[16+l15][k0 + quad*8];
    #pragma unroll
    for (int nt2 = 0; nt2 < 4; nt2++)
      bf[nt2].u = *(const uint4*)(xb + (size_t)(nt2*16+l15)*NC + k0 + quad*8);
    #pragma unroll
    for (int mt = 0; mt < 2; mt++)
      #pragma unroll
      for (int nt2 = 0; nt2 < 4; nt2++)
        acc[mt][nt2] = __builtin_amdgcn_mfma_f32_16x16x32_bf16(af[mt].s, bf[nt2].s, acc[mt][nt2], 0,0,0);
  }
  if (ot < 16){                       // q/k: repack D (row=o,col=n) -> [n][o]
    const float sc = (ot < 8) ? QSC : 1.0f;
    u16* dstbase = (ot < 8) ? qt : kt;
    const int h = (ot < 8) ? ot : ot-8;
    #pragma unroll
    for (int mt = 0; mt < 2; mt++)
      #pragma unroll
      for (int nt2 = 0; nt2 < 4; nt2++){
        uint2 w;
        w.x = (u32)f2b(acc[mt][nt2][0]*sc) | ((u32)f2b(acc[mt][nt2][1]*sc)<<16);
        w.y = (u32)f2b(acc[mt][nt2][2]*sc) | ((u32)f2b(acc[mt][nt2][3]*sc)<<16);
        *(uint2*)&s2[wv][nt2*16+l15][mt*16+quad*4] = w;
      }
    __syncthreads();
    u16* db = dstbase + ((size_t)(b*8+h)*NN + n0w)*32;
    #pragma unroll
    for (int p = 0; p < 4; p++){
      const int n_loc = p*16 + (lane>>2), seg = lane&3;
      uint4 d = *(uint4*)&s2[wv][n_loc][seg*8];
      *(uint4*)(db + (size_t)n_loc*32 + seg*8) = d;
    }
  } else {                            // v: direct [c][n] scalar stores
    const int c0 = o0 - 512;
    #pragma unroll
    for (int mt = 0; mt < 2; mt++)
      #pragma unroll
      for (int nt2 = 0; nt2 < 4; nt2++)
        #pragma unroll
        for (int r = 0; r < 4; r++)
          v[(size_t)(b*NC + c0 + mt*16 + quad*4 + r)*NN + n0w + nt2*16 + l15] = f2b(acc[mt][nt2][r]);
  }
}

// K3: fused MFMA flash attention + LePE + proj.
// Block = 512 thr / 8 waves; wave wv = head wv; block covers image row y
// (32 queries), blockIdx.x = b (XCD-aligned: each XCD sees one batch's K/V).
// Attention+LePE accumulate t[32 q][256 c] bf16 in s_out; proj runs from LDS.
__global__ void __launch_bounds__(512) k_attn_proj(const u16* __restrict__ qt,
                                                   const u16* __restrict__ kt,
                                                   const u16* __restrict__ v,
                                                   const float* __restrict__ lw,
                                                   const float* __restrict__ lb,
                                                   const u16* __restrict__ wpb,
                                                   const float* __restrict__ pbias,
                                                   float* __restrict__ out){
  const int b = blockIdx.x, y = blockIdx.y;
  const int tid = threadIdx.x;
  const int wv = tid >> 6, lane = tid & 63;
  const int l15 = lane & 15, quad = lane >> 4;
  const int h = wv, bh = b*8 + h;
  const int q0 = y*32;

  __shared__ u16 pb[8][2][16][40];     // P round-trip (per-wave region)
  __shared__ u16 vstage[5][256][38];   // LePE halo rows y-2..y+2, all 256 ch; c-stride 19 dw
  __shared__ u16 s_out[32][264];       // t tile [q][c] bf16 (attn + LePE), proj B-source
  u16* pbA = &pb[wv][0][0][0];
  u16* pbB = &pb[wv][1][0][0];

  // --- stage LePE halo: 1280 (row,channel) pairs over 512 threads
  for (int p = tid; p < 1280; p += 512){
    const int rr = p >> 8, c = p & 255;
    const int yy = y - 2 + rr;
    u32* dst32 = (u32*)&vstage[rr][c][0];
    if (yy < 0 || yy > 31){
      #pragma unroll
      for (int j = 0; j < 19; j++) dst32[j] = 0;
    } else {
      const u16* src = v + ((size_t)(b*NC + c))*NN + yy*32;
      uint4 a = *(const uint4*)src;
      uint4 b4 = *(const uint4*)(src+8);
      uint4 c4 = *(const uint4*)(src+16);
      uint4 d4 = *(const uint4*)(src+24);
      dst32[0] = 0;
      dst32[1]=a.x;  dst32[2]=a.y;  dst32[3]=a.z;  dst32[4]=a.w;
      dst32[5]=b4.x; dst32[6]=b4.y; dst32[7]=b4.z; dst32[8]=b4.w;
      dst32[9]=c4.x; dst32[10]=c4.y; dst32[11]=c4.z; dst32[12]=c4.w;
      dst32[13]=d4.x; dst32[14]=d4.y; dst32[15]=d4.z; dst32[16]=d4.w;
      dst32[17]=0; dst32[18]=0;
    }
  }
  __syncthreads();

  const u16* qtb = qt + (size_t)bh*NN*32;
  const u16* ktb = kt + (size_t)bh*NN*32;
  const u16* vbp = v + (size_t)(b*256 + h*32)*NN;

  FR qa, qb_;
  qa.u  = *(const uint4*)(qtb + (size_t)(q0      + l15)*32 + quad*8);
  qb_.u = *(const uint4*)(qtb + (size_t)(q0 + 16 + l15)*32 + quad*8);

  f32x4 z = {0.f,0.f,0.f,0.f};
  f32x4 oA0 = z, oA1 = z, oB0 = z, oB1 = z;
  float denA[4] = {0.f,0.f,0.f,0.f}, denB[4] = {0.f,0.f,0.f,0.f};

  for (int m0 = 0; m0 < NN; m0 += 32){
    FR kf0, kf1, vf0, vf1;
    kf0.u = *(const uint4*)(ktb + (size_t)(m0      + l15)*32 + quad*8);
    kf1.u = *(const uint4*)(ktb + (size_t)(m0 + 16 + l15)*32 + quad*8);
    vf0.u = *(const uint4*)(vbp + (size_t)(l15     )*NN + m0 + quad*8);
    vf1.u = *(const uint4*)(vbp + (size_t)(16 + l15)*NN + m0 + quad*8);

    f32x4 sA0 = __builtin_amdgcn_mfma_f32_16x16x32_bf16(qa.s,  kf0.s, z, 0,0,0);
    f32x4 sA1 = __builtin_amdgcn_mfma_f32_16x16x32_bf16(qa.s,  kf1.s, z, 0,0,0);
    f32x4 sB0 = __builtin_amdgcn_mfma_f32_16x16x32_bf16(qb_.s, kf0.s, z, 0,0,0);
    f32x4 sB1 = __builtin_amdgcn_mfma_f32_16x16x32_bf16(qb_.s, kf1.s, z, 0,0,0);

    #pragma unroll
    for (int r = 0; r < 4; r++){
      float pA0 = __builtin_amdgcn_exp2f(sA0[r]);
      float pA1 = __builtin_amdgcn_exp2f(sA1[r]);
      float pB0 = __builtin_amdgcn_exp2f(sB0[r]);
      float pB1 = __builtin_amdgcn_exp2f(sB1[r]);
      denA[r] += pA0 + pA1;
      denB[r] += pB0 + pB1;
      const int row = (quad*4 + r)*40;
      pbA[row + l15]      = (u16)(__float_as_uint(pA0)>>16);
      pbA[row + 16 + l15] = (u16)(__float_as_uint(pA1)>>16);
      pbB[row + l15]      = (u16)(__float_as_uint(pB0)>>16);
      pbB[row + 16 + l15] = (u16)(__float_as_uint(pB1)>>16);
    }
    FR pfA, pfB;
    pfA.u = *(const uint4*)(pbA + l15*40 + quad*8);
    pfB.u = *(const uint4*)(pbB + l15*40 + quad*8);

    oA0 = __builtin_amdgcn_mfma_f32_16x16x32_bf16(pfA.s, vf0.s, oA0, 0,0,0);
    oA1 = __builtin_amdgcn_mfma_f32_16x16x32_bf16(pfA.s, vf1.s, oA1, 0,0,0);
    oB0 = __builtin_amdgcn_mfma_f32_16x16x32_bf16(pfB.s, vf0.s, oB0, 0,0,0);
    oB1 = __builtin_amdgcn_mfma_f32_16x16x32_bf16(pfB.s, vf1.s, oB1, 0,0,0);
  }
  #pragma unroll
  for (int r = 0; r < 4; r++){
    #pragma unroll
    for (int m = 1; m < 16; m <<= 1){
      denA[r] += __shfl_xor(denA[r], m);
      denB[r] += __shfl_xor(denB[r], m);
    }
  }
  // stage normalized attn out (bf16) into s_out[q][wv*32 + c]
  {
    const int cb = wv*32;
    #pragma unroll
    for (int r = 0; r < 4; r++){
      const int q = quad*4 + r;
      const float iA = 1.f/denA[r], iB = 1.f/denB[r];
      s_out[q][cb + l15]           = f2b(oA0[r]*iA);
      s_out[q][cb + 16 + l15]      = f2b(oA1[r]*iA);
      s_out[q+16][cb + l15]        = f2b(oB0[r]*iB);
      s_out[q+16][cb + 16 + l15]   = f2b(oB1[r]*iB);
    }
  }
  // LePE per lane: channel lc of head wv, 16 x-positions qh*16.. of image row y
  {
    const int lc = lane & 31, qh = lane >> 5;
    float lep[16];
    const float lbias = lb[h*32 + lc];
    #pragma unroll
    for (int i = 0; i < 16; i++) lep[i] = lbias;
    const float* lwc = lw + (size_t)(h*32 + lc)*25;
    #pragma unroll
    for (int ky = 0; ky < 5; ky++){
      const u32* vr = (const u32*)&vstage[ky][wv*32 + lc][0];
      float vv[20];
      #pragma unroll
      for (int jj = 0; jj < 10; jj++){
        u32 pk = vr[qh*8 + jj];
        vv[2*jj]   = pklo(pk);
        vv[2*jj+1] = pkhi(pk);
      }
      const float w0 = lwc[ky*5+0], w1 = lwc[ky*5+1], w2 = lwc[ky*5+2],
                  w3 = lwc[ky*5+3], w4 = lwc[ky*5+4];
      #pragma unroll
      for (int i = 0; i < 16; i++)
        lep[i] += w0*vv[i] + w1*vv[i+1] + w2*vv[i+2] + w3*vv[i+3] + w4*vv[i+4];
    }
    #pragma unroll
    for (int i = 0; i < 16; i++){
      const int q = qh*16 + i;
      u16* p = &s_out[q][wv*32 + lc];
      *p = f2b(b2f(*p) + lep[i]);
    }
  }
  __syncthreads();

  // --- proj: wave wv computes o = wv*32..+31 for the block's 32 n-positions
  {
    const int o0 = wv*32;
    f32x4 accp[2][2];
    #pragma unroll
    for (int mt = 0; mt < 2; mt++)
      #pragma unroll
      for (int nt2 = 0; nt2 < 2; nt2++) accp[mt][nt2] = (f32x4){0.f,0.f,0.f,0.f};
    for (int k0 = 0; k0 < 256; k0 += 32){
      FR af[2], bf2[2];
      af[0].u = *(const uint4*)(wpb + (size_t)(o0 + l15)*NC + k0 + quad*8);
      af[1].u = *(const uint4*)(wpb + (size_t)(o0 + 16 + l15)*NC + k0 + quad*8);
      bf2[0].u = *(const uint4*)&s_out[l15][k0 + quad*8];
      bf2[1].u = *(const uint4*)&s_out[16 + l15][k0 + quad*8];
      #pragma unroll
      for (int mt = 0; mt < 2; mt++)
        #pragma unroll
        for (int nt2 = 0; nt2 < 2; nt2++)
          accp[mt][nt2] = __builtin_amdgcn_mfma_f32_16x16x32_bf16(af[mt].s, bf2[nt2].s, accp[mt][nt2], 0,0,0);
    }
    float bv[2][4];
    #pragma unroll
    for (int mt = 0; mt < 2; mt++)
      #pragma unroll
      for (int r = 0; r < 4; r++) bv[mt][r] = pbias[o0 + mt*16 + quad*4 + r];
    #pragma unroll
    for (int mt = 0; mt < 2; mt++)
      #pragma unroll
      for (int nt2 = 0; nt2 < 2; nt2++)
        #pragma unroll
        for (int r = 0; r < 4; r++)
          out[(size_t)(b*NC + o0 + mt*16 + quad*4 + r)*NN + y*32 + nt2*16 + l15] = accp[mt][nt2][r] + bv[mt][r];
  }
}

extern "C" void kernel_launch(void* const* d_in, const int* in_sizes, int n_in,
                              void* d_out, int out_size, void* d_ws, size_t ws_size,
                              hipStream_t stream){
  const float* x      = (const float*)d_in[0];
  const float* qkv_w  = (const float*)d_in[1];
  const float* proj_w = (const float*)d_in[2];
  const float* proj_b = (const float*)d_in[3];
  const float* lepe_w = (const float*)d_in[4];
  const float* lepe_b = (const float*)d_in[5];
  float* out = (float*)d_out;

  // ws (u16 units): wqb 196608 | wpb 65536 | xt 2M | qt 2M | kt 2M | v 2M
  if (ws_size < (size_t)17301504) return;
  u16* wqb = (u16*)d_ws;
  u16* wpb = wqb + 196608;
  u16* xt  = wpb + 65536;
  u16* qt  = xt + 2097152;
  u16* kt  = qt + 2097152;
  u16* v   = kt + 2097152;

  k_cast<<<dim3(512),      256, 0, stream>>>(qkv_w, proj_w, x, wqb, xt);
  k_qkv <<<dim3(24, 4, 8), 256, 0, stream>>>(wqb, xt, qt, kt, v);
  k_attn_proj<<<dim3(8, 32), 512, 0, stream>>>(qt, kt, v, lepe_w, lepe_b, wpb, proj_b, out);
}